// Round 1
// baseline (5309.389 us; speedup 1.0000x reference)
//
#include <hip/hip_runtime.h>
#include <cstdint>

// Problem dims
#define V_    32000
#define E_    512
#define H_    1024
#define N_    32
#define T_    256
#define TS    255          // steps = T-1
#define COLS  3072         // 3H
#define NJT   192          // 3072/16 col tiles
#define NKT   48           // 1536/32 k tiles
#define NWG_B 64           // phase B workgroups (co-resident: <= 256 CUs)
#define CB_   250          // phase C col blocks (250*128 = 32000)
#define RB_   64           // phase C row blocks (64*128 = 8192, rows 8160..8191 pad)
#define MROW  8192

typedef _Float16 f16;
typedef _Float16 half8 __attribute__((ext_vector_type(8)));
typedef float floatx4 __attribute__((ext_vector_type(4)));

// ---------------- prep kernels ----------------

__global__ void prep_emit16(const float* __restrict__ emit_w, f16* __restrict__ out) {
  const int64_t nchunk = (int64_t)V_ * H_ / 8;
  int64_t i = (int64_t)blockIdx.x * blockDim.x + threadIdx.x;
  for (; i < nchunk; i += (int64_t)gridDim.x * blockDim.x) {
    const float4* src = (const float4*)(emit_w + i * 8);
    float4 a = src[0], b = src[1];
    half8 h;
    h[0] = (f16)a.x; h[1] = (f16)a.y; h[2] = (f16)a.z; h[3] = (f16)a.w;
    h[4] = (f16)b.x; h[5] = (f16)b.y; h[6] = (f16)b.z; h[7] = (f16)b.w;
    *(half8*)(out + i * 8) = h;
  }
}

// Pack [w_ih; w_hh] into MFMA B-fragment order:
// wfrag[jt][kt][lane][8] = W[k = kt*32 + (lane>>4)*8 + i][col = jt*16 + (lane&15)]
// where W[k][col] = k < 512 ? w_ih[col][k] : w_hh[col][k-512]
__global__ void prep_wfrag(const float* __restrict__ w_ih, const float* __restrict__ w_hh,
                           f16* __restrict__ wfrag) {
  int idx = blockIdx.x * blockDim.x + threadIdx.x;   // 192*48*64 = 589824
  if (idx >= NJT * NKT * 64) return;
  int lane = idx & 63;
  int kt   = (idx >> 6) % NKT;
  int jt   = (idx >> 6) / NKT;
  int col  = jt * 16 + (lane & 15);
  int k0   = kt * 32 + (lane >> 4) * 8;
  half8 h;
  if (k0 < E_) {
    const float* src = w_ih + (int64_t)col * E_ + k0;
#pragma unroll
    for (int i = 0; i < 8; ++i) h[i] = (f16)src[i];
  } else {
    const float* src = w_hh + (int64_t)col * H_ + (k0 - E_);
#pragma unroll
    for (int i = 0; i < 8; ++i) h[i] = (f16)src[i];
  }
  *(half8*)(wfrag + (int64_t)idx * 8) = h;
}

// Xemb[t][n][0:512] = (f16) embed_w[words[n][t]][:]
__global__ void prep_xemb(const int* __restrict__ words, const float* __restrict__ embed_w,
                          f16* __restrict__ xemb) {
  int idx = blockIdx.x * blockDim.x + threadIdx.x;   // 255*32*64 = 522240
  if (idx >= TS * N_ * (E_ / 8)) return;
  int u = idx & 63;
  int n = (idx >> 6) & 31;
  int t = idx >> 11;
  int word = words[n * T_ + t];
  const float* src = embed_w + (int64_t)word * E_ + u * 8;
  half8 h;
#pragma unroll
  for (int i = 0; i < 8; ++i) h[i] = (f16)src[i];
  *(half8*)(xemb + (int64_t)(t * N_ + n) * E_ + u * 8) = h;
}

// init Xh (both buffers) from hidden_state; zero barrier words
__global__ void prep_init(const float* __restrict__ h0, f16* __restrict__ xh,
                          unsigned* __restrict__ bar) {
  int idx = blockIdx.x * blockDim.x + threadIdx.x;
  if (idx < N_ * H_) {
    f16 v = (f16)h0[idx];
    xh[idx] = v;
    xh[N_ * H_ + idx] = v;
  }
  if (blockIdx.x == 0 && threadIdx.x < 16) bar[threadIdx.x] = 0;
}

// ---------------- phase B: persistent GRU recurrence ----------------

__device__ inline void gbar(unsigned* cnt, unsigned* gen, unsigned nwg) {
  __syncthreads();
  if (threadIdx.x == 0) {
    __threadfence();  // release all prior global writes device-wide
    unsigned g = __hip_atomic_load(gen, __ATOMIC_RELAXED, __HIP_MEMORY_SCOPE_AGENT);
    unsigned a = __hip_atomic_fetch_add(cnt, 1u, __ATOMIC_ACQ_REL, __HIP_MEMORY_SCOPE_AGENT);
    if (a == nwg - 1u) {
      __hip_atomic_store(cnt, 0u, __ATOMIC_RELAXED, __HIP_MEMORY_SCOPE_AGENT);
      __hip_atomic_fetch_add(gen, 1u, __ATOMIC_ACQ_REL, __HIP_MEMORY_SCOPE_AGENT);
    } else {
      while (__hip_atomic_load(gen, __ATOMIC_ACQUIRE, __HIP_MEMORY_SCOPE_AGENT) == g)
        __builtin_amdgcn_s_sleep(2);
    }
  }
  __syncthreads();
}

// 64 wgs x 256 thr. wg b owns h-cols [b*16, b*16+16); GEMM col tiles jt = b (r), 64+b (z), 128+b (n).
// Waves k-split: wave0 = kt 0..15 (emb part -> gi), waves1..3 = kt 16..47 (h part -> gh).
__launch_bounds__(256, 1)
__global__ void phaseB(const f16* __restrict__ wfrag, const f16* __restrict__ xemb,
                       f16* __restrict__ xh, const float* __restrict__ b_ih,
                       const float* __restrict__ b_hh, f16* __restrict__ hall,
                       float* __restrict__ out, unsigned* __restrict__ bar) {
  const int b = blockIdx.x;
  const int tid = threadIdx.x;
  const int w = tid >> 6;
  const int lane = tid & 63;
  const int l15 = lane & 15, l4 = lane >> 4;

  __shared__ float part[4][32][48];

  // gate-phase constants (thread-invariant across steps)
  const int n_g = tid & 31;
  const int jl0 = tid >> 5, jl1 = 8 + (tid >> 5);
  const int j0 = b * 16 + jl0, j1 = b * 16 + jl1;
  const float biasr0 = b_ih[j0] + b_hh[j0];
  const float biasz0 = b_ih[H_ + j0] + b_hh[H_ + j0];
  const float bihn0 = b_ih[2 * H_ + j0], bhhn0 = b_hh[2 * H_ + j0];
  const float biasr1 = b_ih[j1] + b_hh[j1];
  const float biasz1 = b_ih[H_ + j1] + b_hh[H_ + j1];
  const float bihn1 = b_ih[2 * H_ + j1], bhhn1 = b_hh[2 * H_ + j1];

  const int kt_lo = (w == 0) ? 0 : (16 + (w - 1) * 11);
  const int kt_hi = (w == 0) ? 16 : ((w == 3) ? 48 : (16 + w * 11));

  const f16* wf_r = wfrag + (int64_t)(b) * NKT * 64 * 8;
  const f16* wf_z = wfrag + (int64_t)(64 + b) * NKT * 64 * 8;
  const f16* wf_n = wfrag + (int64_t)(128 + b) * NKT * 64 * 8;

  for (int t = 0; t < TS; ++t) {
    const f16* xh_rd = xh + (t & 1) * (N_ * H_);
    f16* xh_wr = xh + ((t + 1) & 1) * (N_ * H_);

    floatx4 acc[3][2];
#pragma unroll
    for (int a = 0; a < 3; ++a)
#pragma unroll
      for (int m = 0; m < 2; ++m) { acc[a][m][0] = 0.f; acc[a][m][1] = 0.f; acc[a][m][2] = 0.f; acc[a][m][3] = 0.f; }

    for (int kt = kt_lo; kt < kt_hi; ++kt) {
      const int kg = kt * 32 + l4 * 8;
      half8 a0, a1;
      if (kt < 16) {
        const f16* base = xemb + (int64_t)t * (N_ * E_) + kg;
        a0 = *(const half8*)(base + (int64_t)l15 * E_);
        a1 = *(const half8*)(base + (int64_t)(l15 + 16) * E_);
      } else {
        const f16* base = xh_rd + (kg - E_);
        a0 = *(const half8*)(base + (int64_t)l15 * H_);
        a1 = *(const half8*)(base + (int64_t)(l15 + 16) * H_);
      }
      const int64_t boff = ((int64_t)kt * 64 + lane) * 8;
      half8 br = *(const half8*)(wf_r + boff);
      half8 bz = *(const half8*)(wf_z + boff);
      half8 bn = *(const half8*)(wf_n + boff);
      acc[0][0] = __builtin_amdgcn_mfma_f32_16x16x32_f16(a0, br, acc[0][0], 0, 0, 0);
      acc[0][1] = __builtin_amdgcn_mfma_f32_16x16x32_f16(a1, br, acc[0][1], 0, 0, 0);
      acc[1][0] = __builtin_amdgcn_mfma_f32_16x16x32_f16(a0, bz, acc[1][0], 0, 0, 0);
      acc[1][1] = __builtin_amdgcn_mfma_f32_16x16x32_f16(a1, bz, acc[1][1], 0, 0, 0);
      acc[2][0] = __builtin_amdgcn_mfma_f32_16x16x32_f16(a0, bn, acc[2][0], 0, 0, 0);
      acc[2][1] = __builtin_amdgcn_mfma_f32_16x16x32_f16(a1, bn, acc[2][1], 0, 0, 0);
    }

    // C/D layout (m89-verified): col = lane&15, row = (lane>>4)*4 + reg
#pragma unroll
    for (int a = 0; a < 3; ++a)
#pragma unroll
      for (int m = 0; m < 2; ++m)
#pragma unroll
        for (int r = 0; r < 4; ++r)
          part[w][m * 16 + l4 * 4 + r][a * 16 + l15] = acc[a][m][r];
    __syncthreads();

    // gates: items (n_g, jl0) and (n_g, jl1)
#pragma unroll
    for (int it = 0; it < 2; ++it) {
      const int jl = it ? jl1 : jl0;
      const float biasr = it ? biasr1 : biasr0;
      const float biasz = it ? biasz1 : biasz0;
      const float bihn = it ? bihn1 : bihn0;
      const float bhhn = it ? bhhn1 : bhhn0;
      float gr = part[0][n_g][jl] + part[1][n_g][jl] + part[2][n_g][jl] + part[3][n_g][jl] + biasr;
      float gz = part[0][n_g][16 + jl] + part[1][n_g][16 + jl] + part[2][n_g][16 + jl] + part[3][n_g][16 + jl] + biasz;
      float gin = part[0][n_g][32 + jl] + bihn;
      float ghn = part[1][n_g][32 + jl] + part[2][n_g][32 + jl] + part[3][n_g][32 + jl] + bhhn;
      float rg = 1.f / (1.f + __expf(-gr));
      float zg = 1.f / (1.f + __expf(-gz));
      float nn = tanhf(gin + rg * ghn);
      const int j = b * 16 + jl;
      float hold = (float)xh_rd[n_g * H_ + j];
      float hnew = (1.f - zg) * nn + zg * hold;
      xh_wr[n_g * H_ + j] = (f16)hnew;
      hall[(int64_t)(t * N_ + n_g) * H_ + j] = (f16)hnew;
      if (t == TS - 1) out[32 + n_g * H_ + j] = hnew;
    }
    gbar(bar, bar + 1, NWG_B);
  }
}

// ---------------- phase C: logits GEMM + per-row sum(exp) partials ----------------

#define BK 64
#define LDK 72   // +8 f16 pad -> 144B row stride breaks ds_read_b128 bank conflicts

__launch_bounds__(256, 2)
__global__ void phaseC(const f16* __restrict__ hall, const f16* __restrict__ emit16,
                       const float* __restrict__ emit_b, float* __restrict__ spart) {
  const int cb = blockIdx.x % CB_;
  const int rb = blockIdx.x / CB_;
  const int tid = threadIdx.x;
  const int w = tid >> 6, lane = tid & 63;
  const int wm = w & 1, wn = w >> 1;
  const int l15 = lane & 15, l4 = lane >> 4;

  __shared__ f16 lA[128 * LDK];
  __shared__ f16 lB[128 * LDK];
  __shared__ float rs[2][128];

  floatx4 acc[4][4];
#pragma unroll
  for (int mt = 0; mt < 4; ++mt)
#pragma unroll
    for (int nt = 0; nt < 4; ++nt) { acc[mt][nt][0] = 0.f; acc[mt][nt][1] = 0.f; acc[mt][nt][2] = 0.f; acc[mt][nt][3] = 0.f; }

  const f16* gA = hall + (int64_t)rb * 128 * H_;
  const f16* gB = emit16 + (int64_t)cb * 128 * H_;

  for (int kb = 0; kb < 16; ++kb) {
    __syncthreads();
#pragma unroll
    for (int i = 0; i < 4; ++i) {
      int idx = i * 256 + tid;          // 0..1023
      int row = idx >> 3, u = idx & 7;
      int64_t goff = (int64_t)row * H_ + kb * BK + u * 8;
      *(half8*)(lA + row * LDK + u * 8) = *(const half8*)(gA + goff);
      *(half8*)(lB + row * LDK + u * 8) = *(const half8*)(gB + goff);
    }
    __syncthreads();
#pragma unroll
    for (int ks = 0; ks < 2; ++ks) {
      half8 af[4], bf[4];
#pragma unroll
      for (int mt = 0; mt < 4; ++mt)
        af[mt] = *(const half8*)(lA + (wm * 64 + mt * 16 + l15) * LDK + ks * 32 + l4 * 8);
#pragma unroll
      for (int nt = 0; nt < 4; ++nt)
        bf[nt] = *(const half8*)(lB + (wn * 64 + nt * 16 + l15) * LDK + ks * 32 + l4 * 8);
#pragma unroll
      for (int mt = 0; mt < 4; ++mt)
#pragma unroll
        for (int nt = 0; nt < 4; ++nt)
          acc[mt][nt] = __builtin_amdgcn_mfma_f32_16x16x32_f16(af[mt], bf[nt], acc[mt][nt], 0, 0, 0);
    }
  }

  // epilogue: per-row sum of exp(logit + emit_b[col]); |logits| bounded -> no max-sub needed
  float eb[4];
#pragma unroll
  for (int nt = 0; nt < 4; ++nt) eb[nt] = emit_b[cb * 128 + wn * 64 + nt * 16 + l15];

#pragma unroll
  for (int mt = 0; mt < 4; ++mt) {
#pragma unroll
    for (int r = 0; r < 4; ++r) {
      float s = 0.f;
#pragma unroll
      for (int nt = 0; nt < 4; ++nt) s += __expf(acc[mt][nt][r] + eb[nt]);
#pragma unroll
      for (int off = 1; off < 16; off <<= 1) s += __shfl_xor(s, off, 64);
      if (l15 == 0) rs[wn][wm * 64 + mt * 16 + l4 * 4 + r] = s;
    }
  }
  __syncthreads();
  if (tid < 128)
    spart[(int64_t)cb * MROW + rb * 128 + tid] = rs[0][tid] + rs[1][tid];
}

// ---------------- target logits + final reductions ----------------

__global__ void target_dots(const f16* __restrict__ hall, const f16* __restrict__ emit16,
                            const int* __restrict__ words, const float* __restrict__ emit_b,
                            float* __restrict__ tlog) {
  int r = blockIdx.x * 4 + (threadIdx.x >> 6);
  if (r >= TS * N_) return;
  int lane = threadIdx.x & 63;
  int t = r >> 5, n = r & 31;
  int tgt = words[n * T_ + t + 1];
  const f16* ha = hall + (int64_t)r * H_;
  const f16* ebp = emit16 + (int64_t)tgt * H_;
  float s = 0.f;
#pragma unroll
  for (int c = 0; c < 2; ++c) {
    int k = c * 512 + lane * 8;
    half8 a = *(const half8*)(ha + k);
    half8 b = *(const half8*)(ebp + k);
#pragma unroll
    for (int i = 0; i < 8; ++i) s += (float)a[i] * (float)b[i];
  }
#pragma unroll
  for (int off = 1; off < 64; off <<= 1) s += __shfl_xor(s, off, 64);
  if (lane == 0) tlog[r] = s + emit_b[tgt];
}

__global__ void reduce_lse(const float* __restrict__ spart, const float* __restrict__ tlog,
                           float* __restrict__ lval) {
  int r = blockIdx.x * blockDim.x + threadIdx.x;
  if (r >= TS * N_) return;
  float s = 0.f;
  for (int cb = 0; cb < CB_; ++cb) s += spart[(int64_t)cb * MROW + r];
  lval[r] = tlog[r] - logf(s);
}

__global__ void finalize(const float* __restrict__ lval, float* __restrict__ out) {
  __shared__ float ps[8][32];
  int n = threadIdx.x & 31, sl = threadIdx.x >> 5;
  float s = 0.f;
  for (int i = 0; i < 32; ++i) {
    int t = sl * 32 + i;
    if (t < TS) s += lval[t * N_ + n];
  }
  ps[sl][n] = s;
  __syncthreads();
  if (threadIdx.x < 32) {
    float tot = 0.f;
#pragma unroll
    for (int k = 0; k < 8; ++k) tot += ps[k][threadIdx.x];
    out[threadIdx.x] = tot;
  }
}

// ---------------- launch ----------------

extern "C" void kernel_launch(void* const* d_in, const int* in_sizes, int n_in,
                              void* d_out, int out_size, void* d_ws, size_t ws_size,
                              hipStream_t stream) {
  (void)in_sizes; (void)n_in; (void)out_size; (void)ws_size;
  const int*   words   = (const int*)d_in[0];
  const float* h0      = (const float*)d_in[1];
  const float* embed_w = (const float*)d_in[2];
  const float* w_ih    = (const float*)d_in[3];
  const float* w_hh    = (const float*)d_in[4];
  const float* b_ih    = (const float*)d_in[5];
  const float* b_hh    = (const float*)d_in[6];
  const float* emit_w  = (const float*)d_in[7];
  const float* emit_b  = (const float*)d_in[8];
  float* out = (float*)d_out;

  char* ws = (char*)d_ws;
  // ws layout (bytes), total ~108.5 MB
  f16*      emit16 = (f16*)(ws + 0);                // 65,536,000
  f16*      wfrag  = (f16*)(ws + 65536000);         //  9,437,184
  f16*      xemb   = (f16*)(ws + 74973184);         //  8,355,840
  f16*      xh     = (f16*)(ws + 83329024);         //    131,072
  f16*      hall   = (f16*)(ws + 83460096);         // 16,777,216
  float*    spart  = (float*)(ws + 100237312);      //  8,192,000
  float*    tlog   = (float*)(ws + 108429312);      //     32,768
  float*    lval   = (float*)(ws + 108462080);      //     32,768
  unsigned* bar    = (unsigned*)(ws + 108494848);   //         64

  hipLaunchKernelGGL(prep_emit16, dim3(4096), dim3(256), 0, stream, emit_w, emit16);
  hipLaunchKernelGGL(prep_wfrag, dim3(NJT * NKT * 64 / 256), dim3(256), 0, stream, w_ih, w_hh, wfrag);
  hipLaunchKernelGGL(prep_xemb, dim3(TS * N_ * 64 / 256), dim3(256), 0, stream, words, embed_w, xemb);
  hipLaunchKernelGGL(prep_init, dim3(128), dim3(256), 0, stream, h0, xh, bar);
  hipLaunchKernelGGL(phaseB, dim3(NWG_B), dim3(256), 0, stream, wfrag, xemb, xh, b_ih, b_hh, hall, out, bar);
  hipLaunchKernelGGL(phaseC, dim3(RB_ * CB_), dim3(256), 0, stream, hall, emit16, emit_b, spart);
  hipLaunchKernelGGL(target_dots, dim3((TS * N_ + 3) / 4), dim3(256), 0, stream, hall, emit16, words, emit_b, tlog);
  hipLaunchKernelGGL(reduce_lse, dim3((TS * N_ + 255) / 256), dim3(256), 0, stream, spart, tlog, lval);
  hipLaunchKernelGGL(finalize, dim3(1), dim3(256), 0, stream, lval, out);
}

// Round 2
// 2995.176 us; speedup vs baseline: 1.7726x; 1.7726x over previous
//
#include <hip/hip_runtime.h>
#include <cstdint>

// Problem dims
#define V_    32000
#define E_    512
#define H_    1024
#define N_    32
#define T_    256
#define TS    255          // steps = T-1
#define NWG_B 64           // phase B workgroups (co-resident: <= 256 CUs)
#define CB_   250          // phase C col blocks (250*128 = 32000)
#define RB_   64           // phase C row blocks (64*128 = 8192; rows 8160..8191 pad)
#define MROW  8192
#define GI_CB 24           // Gi GEMM col blocks (24*128 = 3072)

typedef _Float16 f16;
typedef _Float16 half8 __attribute__((ext_vector_type(8)));
typedef float floatx4 __attribute__((ext_vector_type(4)));

// ---------------- prep kernels ----------------

__global__ void prep_emit16(const float* __restrict__ emit_w, f16* __restrict__ out) {
  const int64_t nchunk = (int64_t)V_ * H_ / 8;
  int64_t i = (int64_t)blockIdx.x * blockDim.x + threadIdx.x;
  for (; i < nchunk; i += (int64_t)gridDim.x * blockDim.x) {
    const float4* src = (const float4*)(emit_w + i * 8);
    float4 a = src[0], b = src[1];
    half8 h;
    h[0] = (f16)a.x; h[1] = (f16)a.y; h[2] = (f16)a.z; h[3] = (f16)a.w;
    h[4] = (f16)b.x; h[5] = (f16)b.y; h[6] = (f16)b.z; h[7] = (f16)b.w;
    *(half8*)(out + i * 8) = h;
  }
}

// w_hh -> MFMA B-fragment order: whh[(jt*32+kt)*64+lane][8] =
//   w_hh[col = jt*16 + (lane&15)][k = kt*32 + (lane>>4)*8 + i], jt in [0,192), kt in [0,32)
__global__ void prep_whh(const float* __restrict__ w_hh, f16* __restrict__ whh) {
  int idx = blockIdx.x * blockDim.x + threadIdx.x;   // 192*32*64 = 393216
  if (idx >= 192 * 32 * 64) return;
  int lane = idx & 63;
  int kt   = (idx >> 6) & 31;
  int jt   = (idx >> 6) >> 5;
  int col  = jt * 16 + (lane & 15);
  int k0   = kt * 32 + (lane >> 4) * 8;
  const float* src = w_hh + (int64_t)col * H_ + k0;
  half8 h;
#pragma unroll
  for (int i = 0; i < 8; ++i) h[i] = (f16)src[i];
  *(half8*)(whh + (int64_t)idx * 8) = h;
}

// w_ih f32[3072][512] -> f16 row-major (B operand of Gi GEMM)
__global__ void prep_wih16(const float* __restrict__ w_ih, f16* __restrict__ out) {
  int idx = blockIdx.x * blockDim.x + threadIdx.x;   // 3072*512/8 = 196608
  if (idx >= 3072 * 512 / 8) return;
  const float4* src = (const float4*)(w_ih + (int64_t)idx * 8);
  float4 a = src[0], b = src[1];
  half8 h;
  h[0] = (f16)a.x; h[1] = (f16)a.y; h[2] = (f16)a.z; h[3] = (f16)a.w;
  h[4] = (f16)b.x; h[5] = (f16)b.y; h[6] = (f16)b.z; h[7] = (f16)b.w;
  *(half8*)(out + (int64_t)idx * 8) = h;
}

// Xemb[t*32+n][0:512] = (f16) embed_w[words[n][t]][:]
__global__ void prep_xemb(const int* __restrict__ words, const float* __restrict__ embed_w,
                          f16* __restrict__ xemb) {
  int idx = blockIdx.x * blockDim.x + threadIdx.x;   // 255*32*64 = 522240
  if (idx >= TS * N_ * (E_ / 8)) return;
  int u = idx & 63;
  int n = (idx >> 6) & 31;
  int t = idx >> 11;
  int word = words[n * T_ + t];
  const float* src = embed_w + (int64_t)word * E_ + u * 8;
  half8 h;
#pragma unroll
  for (int i = 0; i < 8; ++i) h[i] = (f16)src[i];
  *(half8*)(xemb + (int64_t)(t * N_ + n) * E_ + u * 8) = h;
}

// init Xh (both buffers) from hidden_state; zero barrier slots
__global__ void prep_init(const float* __restrict__ h0, f16* __restrict__ xh,
                          unsigned* __restrict__ slots) {
  int idx = blockIdx.x * blockDim.x + threadIdx.x;
  if (idx < N_ * H_) {
    f16 v = (f16)h0[idx];
    xh[idx] = v;
    xh[N_ * H_ + idx] = v;
  }
  if (idx < 1024) slots[idx] = 0;
}

// ---------------- Gi GEMM: Xemb[8192x512] @ wih16^T -> Gi2[t][3072][32] f16 ----------------

#define LDK 72   // +8 f16 pad per 64-f16 row slice: breaks ds_read_b128 bank conflicts

__launch_bounds__(256, 2)
__global__ void gi_gemm(const f16* __restrict__ xemb, const f16* __restrict__ wih16,
                        f16* __restrict__ gi2) {
  const int cb = blockIdx.x % GI_CB;
  const int rb = blockIdx.x / GI_CB;
  const int tid = threadIdx.x;
  const int w = tid >> 6, lane = tid & 63;
  const int wm = w & 1, wn = w >> 1;
  const int l15 = lane & 15, l4 = lane >> 4;

  __shared__ f16 lA[128 * LDK];
  __shared__ f16 lB[128 * LDK];

  floatx4 acc[4][4];
#pragma unroll
  for (int mt = 0; mt < 4; ++mt)
#pragma unroll
    for (int nt = 0; nt < 4; ++nt) { acc[mt][nt][0] = 0.f; acc[mt][nt][1] = 0.f; acc[mt][nt][2] = 0.f; acc[mt][nt][3] = 0.f; }

  const f16* gA = xemb + (int64_t)rb * 128 * E_;
  const f16* gB = wih16 + (int64_t)cb * 128 * E_;

  for (int kb = 0; kb < 8; ++kb) {
    __syncthreads();
#pragma unroll
    for (int i = 0; i < 4; ++i) {
      int idx = i * 256 + tid;
      int row = idx >> 3, u = idx & 7;
      int64_t goff = (int64_t)row * E_ + kb * 64 + u * 8;
      *(half8*)(lA + row * LDK + u * 8) = *(const half8*)(gA + goff);
      *(half8*)(lB + row * LDK + u * 8) = *(const half8*)(gB + goff);
    }
    __syncthreads();
#pragma unroll
    for (int ks = 0; ks < 2; ++ks) {
      half8 af[4], bf[4];
#pragma unroll
      for (int mt = 0; mt < 4; ++mt)
        af[mt] = *(const half8*)(lA + (wm * 64 + mt * 16 + l15) * LDK + ks * 32 + l4 * 8);
#pragma unroll
      for (int nt = 0; nt < 4; ++nt)
        bf[nt] = *(const half8*)(lB + (wn * 64 + nt * 16 + l15) * LDK + ks * 32 + l4 * 8);
#pragma unroll
      for (int mt = 0; mt < 4; ++mt)
#pragma unroll
        for (int nt = 0; nt < 4; ++nt)
          acc[mt][nt] = __builtin_amdgcn_mfma_f32_16x16x32_f16(af[mt], bf[nt], acc[mt][nt], 0, 0, 0);
    }
  }

  // epilogue: Gi2[((t*3072)+col)*32 + n], col = cb*128 + wn*64 + nt*16 + l15
#pragma unroll
  for (int mt = 0; mt < 4; ++mt) {
#pragma unroll
    for (int r = 0; r < 4; ++r) {
      int g = rb * 128 + wm * 64 + mt * 16 + l4 * 4 + r;
      if (g < TS * N_) {
        int tt = g >> 5, n = g & 31;
        f16* gb = gi2 + ((int64_t)tt * 3072 + cb * 128 + wn * 64) * 32 + n;
#pragma unroll
        for (int nt = 0; nt < 4; ++nt)
          gb[(nt * 16 + l15) * 32] = (f16)acc[mt][nt][r];
      }
    }
  }
}

// ---------------- phase B: persistent GRU recurrence (h-part only) ----------------

// contention-free flag barrier: 64 slots on distinct cachelines, monotone counters
__device__ inline void gbar2(unsigned* slots, unsigned tval, int b) {
  __syncthreads();   // drains each wave's vmcnt -> all wg stores in L2
  if (threadIdx.x < 64) {
    if (threadIdx.x == 0) {
      __threadfence();  // agent release: writeback L2 so remote XCDs can see xh
      __hip_atomic_store(slots + b * 16, tval, __ATOMIC_RELAXED, __HIP_MEMORY_SCOPE_AGENT);
    }
    unsigned* my = slots + threadIdx.x * 16;
    while (__hip_atomic_load(my, __ATOMIC_RELAXED, __HIP_MEMORY_SCOPE_AGENT) < tval)
      __builtin_amdgcn_s_sleep(1);
    __threadfence();    // agent acquire: invalidate L1 (+L2 stale lines)
  }
  __syncthreads();
}

// 64 wgs x 512 thr (8 waves). wg b owns h-cols [b*16, b*16+16).
// Wave w covers kt in [w*4, w*4+4) of 32 (K = H = 1024). Weights live in VGPRs.
__launch_bounds__(512, 1)
__global__ void phaseB(const f16* __restrict__ whh, const f16* __restrict__ gi2,
                       f16* __restrict__ xh, const float* __restrict__ b_ih,
                       const float* __restrict__ b_hh, f16* __restrict__ hall,
                       float* __restrict__ out, unsigned* __restrict__ slots) {
  const int b = blockIdx.x;
  const int tid = threadIdx.x;
  const int w = tid >> 6;
  const int lane = tid & 63;
  const int l15 = lane & 15, l4 = lane >> 4;

  __shared__ float part[8][32][49];   // padded: 49*4B stride -> conflict-free gate reads

  // gate-phase constants: one (n, jl) item per thread
  const int n_g = tid & 31;
  const int jl = tid >> 5;            // 0..15
  const int j = b * 16 + jl;
  const float biasr = b_ih[j] + b_hh[j];
  const float biasz = b_ih[H_ + j] + b_hh[H_ + j];
  const float bihn = b_ih[2 * H_ + j];
  const float bhhn = b_hh[2 * H_ + j];

  // preload w_hh fragments (3 gates x 4 ktiles x 16B = 48 VGPRs)
  half8 wf[3][4];
#pragma unroll
  for (int g = 0; g < 3; ++g) {
    int jt = g * 64 + b;
#pragma unroll
    for (int k = 0; k < 4; ++k)
      wf[g][k] = *(const half8*)(whh + (((int64_t)jt * 32 + (w * 4 + k)) * 64 + lane) * 8);
  }

  for (int t = 0; t < TS; ++t) {
    const f16* xh_rd = xh + (t & 1) * (N_ * H_);
    f16* xh_wr = xh + ((t + 1) & 1) * (N_ * H_);

    // early independent loads (Gi + h_old) to overlap with MFMA
    const f16* gbase = gi2 + (int64_t)t * 3072 * 32 + n_g;
    float gvr = (float)gbase[(int64_t)j * 32];
    float gvz = (float)gbase[(int64_t)(H_ + j) * 32];
    float gvn = (float)gbase[(int64_t)(2 * H_ + j) * 32];
    float hold = (float)xh_rd[n_g * H_ + j];

    floatx4 acc[3][2];
#pragma unroll
    for (int g = 0; g < 3; ++g)
#pragma unroll
      for (int m = 0; m < 2; ++m) { acc[g][m][0] = 0.f; acc[g][m][1] = 0.f; acc[g][m][2] = 0.f; acc[g][m][3] = 0.f; }

    half8 a0[4], a1[4];
#pragma unroll
    for (int k = 0; k < 4; ++k) {
      const f16* base = xh_rd + (w * 4 + k) * 32 + l4 * 8;
      a0[k] = *(const half8*)(base + l15 * H_);
      a1[k] = *(const half8*)(base + (l15 + 16) * H_);
    }
#pragma unroll
    for (int k = 0; k < 4; ++k) {
#pragma unroll
      for (int g = 0; g < 3; ++g) {
        acc[g][0] = __builtin_amdgcn_mfma_f32_16x16x32_f16(a0[k], wf[g][k], acc[g][0], 0, 0, 0);
        acc[g][1] = __builtin_amdgcn_mfma_f32_16x16x32_f16(a1[k], wf[g][k], acc[g][1], 0, 0, 0);
      }
    }

    // C/D layout: col = lane&15, row = (lane>>4)*4 + reg
#pragma unroll
    for (int g = 0; g < 3; ++g)
#pragma unroll
      for (int m = 0; m < 2; ++m)
#pragma unroll
        for (int r = 0; r < 4; ++r)
          part[w][m * 16 + l4 * 4 + r][g * 16 + l15] = acc[g][m][r];
    __syncthreads();

    float gr = biasr + gvr, gz = biasz + gvz, gin = bihn + gvn, ghn = bhhn;
#pragma unroll
    for (int ww = 0; ww < 8; ++ww) {
      gr += part[ww][n_g][jl];
      gz += part[ww][n_g][16 + jl];
      ghn += part[ww][n_g][32 + jl];
    }
    float rg = 1.f / (1.f + __expf(-gr));
    float zg = 1.f / (1.f + __expf(-gz));
    float nn = tanhf(gin + rg * ghn);
    float hnew = (1.f - zg) * nn + zg * hold;
    xh_wr[n_g * H_ + j] = (f16)hnew;
    hall[((int64_t)t * N_ + n_g) * H_ + j] = (f16)hnew;
    if (t == TS - 1) out[32 + n_g * H_ + j] = hnew;

    gbar2(slots, (unsigned)(t + 1), b);
  }
}

// ---------------- phase C: logits GEMM + per-row sum(exp) partials ----------------

__launch_bounds__(256, 2)
__global__ void phaseC(const f16* __restrict__ hall, const f16* __restrict__ emit16,
                       const float* __restrict__ emit_b, float* __restrict__ spart) {
  const int cb = blockIdx.x % CB_;
  const int rb = blockIdx.x / CB_;
  const int tid = threadIdx.x;
  const int w = tid >> 6, lane = tid & 63;
  const int wm = w & 1, wn = w >> 1;
  const int l15 = lane & 15, l4 = lane >> 4;

  __shared__ f16 lA[128 * LDK];
  __shared__ f16 lB[128 * LDK];
  __shared__ float rs[2][128];

  floatx4 acc[4][4];
#pragma unroll
  for (int mt = 0; mt < 4; ++mt)
#pragma unroll
    for (int nt = 0; nt < 4; ++nt) { acc[mt][nt][0] = 0.f; acc[mt][nt][1] = 0.f; acc[mt][nt][2] = 0.f; acc[mt][nt][3] = 0.f; }

  const f16* gA = hall + (int64_t)rb * 128 * H_;
  const f16* gB = emit16 + (int64_t)cb * 128 * H_;

  for (int kb = 0; kb < 16; ++kb) {
    __syncthreads();
#pragma unroll
    for (int i = 0; i < 4; ++i) {
      int idx = i * 256 + tid;
      int row = idx >> 3, u = idx & 7;
      int64_t goff = (int64_t)row * H_ + kb * 64 + u * 8;
      *(half8*)(lA + row * LDK + u * 8) = *(const half8*)(gA + goff);
      *(half8*)(lB + row * LDK + u * 8) = *(const half8*)(gB + goff);
    }
    __syncthreads();
#pragma unroll
    for (int ks = 0; ks < 2; ++ks) {
      half8 af[4], bf[4];
#pragma unroll
      for (int mt = 0; mt < 4; ++mt)
        af[mt] = *(const half8*)(lA + (wm * 64 + mt * 16 + l15) * LDK + ks * 32 + l4 * 8);
#pragma unroll
      for (int nt = 0; nt < 4; ++nt)
        bf[nt] = *(const half8*)(lB + (wn * 64 + nt * 16 + l15) * LDK + ks * 32 + l4 * 8);
#pragma unroll
      for (int mt = 0; mt < 4; ++mt)
#pragma unroll
        for (int nt = 0; nt < 4; ++nt)
          acc[mt][nt] = __builtin_amdgcn_mfma_f32_16x16x32_f16(af[mt], bf[nt], acc[mt][nt], 0, 0, 0);
    }
  }

  // |logits| bounded (|h|<1, |emit_w|<~0.032) -> no max-subtraction needed
  float eb[4];
#pragma unroll
  for (int nt = 0; nt < 4; ++nt) eb[nt] = emit_b[cb * 128 + wn * 64 + nt * 16 + l15];

#pragma unroll
  for (int mt = 0; mt < 4; ++mt) {
#pragma unroll
    for (int r = 0; r < 4; ++r) {
      float s = 0.f;
#pragma unroll
      for (int nt = 0; nt < 4; ++nt) s += __expf(acc[mt][nt][r] + eb[nt]);
#pragma unroll
      for (int off = 1; off < 16; off <<= 1) s += __shfl_xor(s, off, 64);
      if (l15 == 0) rs[wn][wm * 64 + mt * 16 + l4 * 4 + r] = s;
    }
  }
  __syncthreads();
  if (tid < 128)
    spart[(int64_t)cb * MROW + rb * 128 + tid] = rs[0][tid] + rs[1][tid];
}

// ---------------- target logits + final reductions ----------------

__global__ void target_dots(const f16* __restrict__ hall, const f16* __restrict__ emit16,
                            const int* __restrict__ words, const float* __restrict__ emit_b,
                            float* __restrict__ tlog) {
  int r = blockIdx.x * 4 + (threadIdx.x >> 6);
  if (r >= TS * N_) return;
  int lane = threadIdx.x & 63;
  int t = r >> 5, n = r & 31;
  int tgt = words[n * T_ + t + 1];
  const f16* ha = hall + (int64_t)r * H_;
  const f16* ebp = emit16 + (int64_t)tgt * H_;
  float s = 0.f;
#pragma unroll
  for (int c = 0; c < 2; ++c) {
    int k = c * 512 + lane * 8;
    half8 a = *(const half8*)(ha + k);
    half8 b = *(const half8*)(ebp + k);
#pragma unroll
    for (int i = 0; i < 8; ++i) s += (float)a[i] * (float)b[i];
  }
#pragma unroll
  for (int off = 1; off < 64; off <<= 1) s += __shfl_xor(s, off, 64);
  if (lane == 0) tlog[r] = s + emit_b[tgt];
}

__global__ void reduce_lse(const float* __restrict__ spart, const float* __restrict__ tlog,
                           float* __restrict__ lval) {
  int r = blockIdx.x * blockDim.x + threadIdx.x;
  if (r >= TS * N_) return;
  float s = 0.f;
  for (int cb = 0; cb < CB_; ++cb) s += spart[(int64_t)cb * MROW + r];
  lval[r] = tlog[r] - logf(s);
}

__global__ void finalize(const float* __restrict__ lval, float* __restrict__ out) {
  __shared__ float ps[8][32];
  int n = threadIdx.x & 31, sl = threadIdx.x >> 5;
  float s = 0.f;
  for (int i = 0; i < 32; ++i) {
    int t = sl * 32 + i;
    if (t < TS) s += lval[t * N_ + n];
  }
  ps[sl][n] = s;
  __syncthreads();
  if (threadIdx.x < 32) {
    float tot = 0.f;
#pragma unroll
    for (int k = 0; k < 8; ++k) tot += ps[k][threadIdx.x];
    out[threadIdx.x] = tot;
  }
}

// ---------------- launch ----------------

extern "C" void kernel_launch(void* const* d_in, const int* in_sizes, int n_in,
                              void* d_out, int out_size, void* d_ws, size_t ws_size,
                              hipStream_t stream) {
  (void)in_sizes; (void)n_in; (void)out_size; (void)ws_size;
  const int*   words   = (const int*)d_in[0];
  const float* h0      = (const float*)d_in[1];
  const float* embed_w = (const float*)d_in[2];
  const float* w_ih    = (const float*)d_in[3];
  const float* w_hh    = (const float*)d_in[4];
  const float* b_ih    = (const float*)d_in[5];
  const float* b_hh    = (const float*)d_in[6];
  const float* emit_w  = (const float*)d_in[7];
  const float* emit_b  = (const float*)d_in[8];
  float* out = (float*)d_out;

  char* ws = (char*)d_ws;
  // ws layout (bytes), total ~100.3 MB. Aliases:
  //  - big region: Gi2 (f16, 50.1 MB, dead after phaseB) then emit16 (65.5 MB, built after phaseB)
  //  - spart (8.19 MB, phaseC) aliases wih16+xemb (11.5 MB, dead after gi_gemm)
  f16*      big    = (f16*)(ws + 0);                // 65,536,000
  f16*      gi2    = big;
  f16*      emit16 = big;
  f16*      whh    = (f16*)(ws + 65536000);         //  6,291,456
  f16*      wih16  = (f16*)(ws + 71827456);         //  3,145,728
  float*    spart  = (float*)(ws + 71827456);       //  8,192,000 (alias)
  f16*      xemb   = (f16*)(ws + 74973184);         //  8,388,608 (8192 rows x 512)
  f16*      xh     = (f16*)(ws + 83361792);         //    131,072
  f16*      hall   = (f16*)(ws + 83492864);         // 16,777,216
  float*    tlog   = (float*)(ws + 100270080);      //     32,640
  float*    lval   = (float*)(ws + 100302720);      //     32,640
  unsigned* slots  = (unsigned*)(ws + 100335360);   //      4,096

  hipLaunchKernelGGL(prep_whh, dim3(1536), dim3(256), 0, stream, w_hh, whh);
  hipLaunchKernelGGL(prep_wih16, dim3(768), dim3(256), 0, stream, w_ih, wih16);
  hipLaunchKernelGGL(prep_xemb, dim3(2040), dim3(256), 0, stream, words, embed_w, xemb);
  hipLaunchKernelGGL(prep_init, dim3(128), dim3(256), 0, stream, h0, xh, slots);
  hipLaunchKernelGGL(gi_gemm, dim3(RB_ * GI_CB), dim3(256), 0, stream, xemb, wih16, gi2);
  hipLaunchKernelGGL(phaseB, dim3(NWG_B), dim3(512), 0, stream, whh, gi2, xh, b_ih, b_hh, hall, out, slots);
  hipLaunchKernelGGL(prep_emit16, dim3(4096), dim3(256), 0, stream, emit_w, emit16);
  hipLaunchKernelGGL(phaseC, dim3(RB_ * CB_), dim3(256), 0, stream, hall, emit16, emit_b, spart);
  hipLaunchKernelGGL(target_dots, dim3((TS * N_ + 3) / 4), dim3(256), 0, stream, hall, emit16, words, emit_b, tlog);
  hipLaunchKernelGGL(reduce_lse, dim3((TS * N_ + 255) / 256), dim3(256), 0, stream, spart, tlog, lval);
  hipLaunchKernelGGL(finalize, dim3(1), dim3(256), 0, stream, lval, out);
}

// Round 3
// 2660.885 us; speedup vs baseline: 1.9953x; 1.1256x over previous
//
#include <hip/hip_runtime.h>
#include <cstdint>

// Problem dims
#define V_    32000
#define E_    512
#define H_    1024
#define N_    32
#define T_    256
#define TS    255          // steps = T-1
#define NWG_B 64           // phase B workgroups (co-resident: <= 256 CUs)
#define CB_   250          // phase C col blocks (250*128 = 32000)
#define RB_   64           // phase C row blocks (64*128 = 8192; rows 8160..8191 pad)
#define MROW  8192
#define GI_CB 24           // Gi GEMM col blocks (24*128 = 3072)

typedef _Float16 f16;
typedef _Float16 half8 __attribute__((ext_vector_type(8)));
typedef float floatx4 __attribute__((ext_vector_type(4)));
typedef unsigned long long u64;

// ---------------- prep kernels ----------------

__global__ void prep_emit16(const float* __restrict__ emit_w, f16* __restrict__ out) {
  const int64_t nchunk = (int64_t)V_ * H_ / 8;
  int64_t i = (int64_t)blockIdx.x * blockDim.x + threadIdx.x;
  for (; i < nchunk; i += (int64_t)gridDim.x * blockDim.x) {
    const float4* src = (const float4*)(emit_w + i * 8);
    float4 a = src[0], b = src[1];
    half8 h;
    h[0] = (f16)a.x; h[1] = (f16)a.y; h[2] = (f16)a.z; h[3] = (f16)a.w;
    h[4] = (f16)b.x; h[5] = (f16)b.y; h[6] = (f16)b.z; h[7] = (f16)b.w;
    *(half8*)(out + i * 8) = h;
  }
}

// w_hh -> MFMA B-fragment order: whh[(jt*32+kt)*64+lane][8] =
//   w_hh[col = jt*16 + (lane&15)][k = kt*32 + (lane>>4)*8 + i], jt in [0,192), kt in [0,32)
__global__ void prep_whh(const float* __restrict__ w_hh, f16* __restrict__ whh) {
  int idx = blockIdx.x * blockDim.x + threadIdx.x;   // 192*32*64 = 393216
  if (idx >= 192 * 32 * 64) return;
  int lane = idx & 63;
  int kt   = (idx >> 6) & 31;
  int jt   = (idx >> 6) >> 5;
  int col  = jt * 16 + (lane & 15);
  int k0   = kt * 32 + (lane >> 4) * 8;
  const float* src = w_hh + (int64_t)col * H_ + k0;
  half8 h;
#pragma unroll
  for (int i = 0; i < 8; ++i) h[i] = (f16)src[i];
  *(half8*)(whh + (int64_t)idx * 8) = h;
}

// w_ih f32[3072][512] -> f16 row-major (B operand of Gi GEMM)
__global__ void prep_wih16(const float* __restrict__ w_ih, f16* __restrict__ out) {
  int idx = blockIdx.x * blockDim.x + threadIdx.x;   // 3072*512/8 = 196608
  if (idx >= 3072 * 512 / 8) return;
  const float4* src = (const float4*)(w_ih + (int64_t)idx * 8);
  float4 a = src[0], b = src[1];
  half8 h;
  h[0] = (f16)a.x; h[1] = (f16)a.y; h[2] = (f16)a.z; h[3] = (f16)a.w;
  h[4] = (f16)b.x; h[5] = (f16)b.y; h[6] = (f16)b.z; h[7] = (f16)b.w;
  *(half8*)(out + (int64_t)idx * 8) = h;
}

// Xemb[t*32+n][0:512] = (f16) embed_w[words[n][t]][:]
__global__ void prep_xemb(const int* __restrict__ words, const float* __restrict__ embed_w,
                          f16* __restrict__ xemb) {
  int idx = blockIdx.x * blockDim.x + threadIdx.x;   // 255*32*64 = 522240
  if (idx >= TS * N_ * (E_ / 8)) return;
  int u = idx & 63;
  int n = (idx >> 6) & 31;
  int t = idx >> 11;
  int word = words[n * T_ + t];
  const float* src = embed_w + (int64_t)word * E_ + u * 8;
  half8 h;
#pragma unroll
  for (int i = 0; i < 8; ++i) h[i] = (f16)src[i];
  *(half8*)(xemb + (int64_t)(t * N_ + n) * E_ + u * 8) = h;
}

// init Xh (both buffers) from hidden_state; zero barrier slots
__global__ void prep_init(const float* __restrict__ h0, f16* __restrict__ xh,
                          unsigned* __restrict__ slots) {
  int idx = blockIdx.x * blockDim.x + threadIdx.x;
  if (idx < N_ * H_) {
    f16 v = (f16)h0[idx];
    xh[idx] = v;
    xh[N_ * H_ + idx] = v;
  }
  if (idx < 1024) slots[idx] = 0;
}

// ---------------- Gi GEMM: Xemb[8192x512] @ wih16^T -> Gi2[t][3072][32] f16 ----------------

#define LDK 72   // +8 f16 pad per 64-f16 row slice: breaks ds_read_b128 bank conflicts

__launch_bounds__(256, 2)
__global__ void gi_gemm(const f16* __restrict__ xemb, const f16* __restrict__ wih16,
                        f16* __restrict__ gi2) {
  const int cb = blockIdx.x % GI_CB;
  const int rb = blockIdx.x / GI_CB;
  const int tid = threadIdx.x;
  const int w = tid >> 6, lane = tid & 63;
  const int wm = w & 1, wn = w >> 1;
  const int l15 = lane & 15, l4 = lane >> 4;

  __shared__ f16 lA[128 * LDK];
  __shared__ f16 lB[128 * LDK];

  floatx4 acc[4][4];
#pragma unroll
  for (int mt = 0; mt < 4; ++mt)
#pragma unroll
    for (int nt = 0; nt < 4; ++nt) { acc[mt][nt][0] = 0.f; acc[mt][nt][1] = 0.f; acc[mt][nt][2] = 0.f; acc[mt][nt][3] = 0.f; }

  const f16* gA = xemb + (int64_t)rb * 128 * E_;
  const f16* gB = wih16 + (int64_t)cb * 128 * E_;

  for (int kb = 0; kb < 8; ++kb) {
    __syncthreads();
#pragma unroll
    for (int i = 0; i < 4; ++i) {
      int idx = i * 256 + tid;
      int row = idx >> 3, u = idx & 7;
      int64_t goff = (int64_t)row * E_ + kb * 64 + u * 8;
      *(half8*)(lA + row * LDK + u * 8) = *(const half8*)(gA + goff);
      *(half8*)(lB + row * LDK + u * 8) = *(const half8*)(gB + goff);
    }
    __syncthreads();
#pragma unroll
    for (int ks = 0; ks < 2; ++ks) {
      half8 af[4], bf[4];
#pragma unroll
      for (int mt = 0; mt < 4; ++mt)
        af[mt] = *(const half8*)(lA + (wm * 64 + mt * 16 + l15) * LDK + ks * 32 + l4 * 8);
#pragma unroll
      for (int nt = 0; nt < 4; ++nt)
        bf[nt] = *(const half8*)(lB + (wn * 64 + nt * 16 + l15) * LDK + ks * 32 + l4 * 8);
#pragma unroll
      for (int mt = 0; mt < 4; ++mt)
#pragma unroll
        for (int nt = 0; nt < 4; ++nt)
          acc[mt][nt] = __builtin_amdgcn_mfma_f32_16x16x32_f16(af[mt], bf[nt], acc[mt][nt], 0, 0, 0);
    }
  }

  // epilogue: Gi2[((t*3072)+col)*32 + n], col = cb*128 + wn*64 + nt*16 + l15
#pragma unroll
  for (int mt = 0; mt < 4; ++mt) {
#pragma unroll
    for (int r = 0; r < 4; ++r) {
      int g = rb * 128 + wm * 64 + mt * 16 + l4 * 4 + r;
      if (g < TS * N_) {
        int tt = g >> 5, n = g & 31;
        f16* gb = gi2 + ((int64_t)tt * 3072 + cb * 128 + wn * 64) * 32 + n;
#pragma unroll
        for (int nt = 0; nt < 4; ++nt)
          gb[(nt * 16 + l15) * 32] = (f16)acc[mt][nt][r];
      }
    }
  }
}

// ---------------- phase B: persistent GRU recurrence (h-part only) ----------------

__device__ inline u64 aload64(const void* p) {
  return __hip_atomic_load((const u64*)p, __ATOMIC_RELAXED, __HIP_MEMORY_SCOPE_AGENT);
}
__device__ inline unsigned aload32(const void* p) {
  return __hip_atomic_load((const unsigned*)p, __ATOMIC_RELAXED, __HIP_MEMORY_SCOPE_AGENT);
}

// fence-free barrier: all shared data moves via per-access-coherent (sc1) atomics,
// so no L2 writeback/invalidate is needed. 64 slots on distinct cachelines,
// monotone step counters; lane i of wave 0 polls slot i.
__device__ inline void gbar3(unsigned* slots, unsigned tval, int b) {
  __syncthreads();   // emits s_waitcnt vmcnt(0) before s_barrier: all stores acked
  if (threadIdx.x == 0) {
    __builtin_amdgcn_s_waitcnt(0);  // belt and suspenders
    __hip_atomic_store(slots + b * 16, tval, __ATOMIC_RELAXED, __HIP_MEMORY_SCOPE_AGENT);
  }
  if (threadIdx.x < 64) {
    unsigned* my = slots + threadIdx.x * 16;
    while (__hip_atomic_load(my, __ATOMIC_RELAXED, __HIP_MEMORY_SCOPE_AGENT) < tval)
      __builtin_amdgcn_s_sleep(1);
  }
  __syncthreads();
}

// 64 wgs x 512 thr (8 waves). wg b owns h-cols [b*16, b*16+16).
// Wave w covers kt in [w*4, w*4+4) of 32 (K = H = 1024). Weights live in VGPRs.
__launch_bounds__(512, 1)
__global__ void phaseB(const f16* __restrict__ whh, const f16* __restrict__ gi2,
                       f16* __restrict__ xh, const float* __restrict__ b_ih,
                       const float* __restrict__ b_hh, f16* __restrict__ hall,
                       float* __restrict__ out, unsigned* __restrict__ slots) {
  const int b = blockIdx.x;
  const int tid = threadIdx.x;
  const int w = tid >> 6;
  const int lane = tid & 63;
  const int l15 = lane & 15, l4 = lane >> 4;

  __shared__ float part[8][32][49];   // padded: 49*4B stride -> conflict-free gate reads

  // gate-phase constants: one (n, jl) item per thread
  const int n_g = tid & 31;
  const int jl = tid >> 5;            // 0..15
  const int j = b * 16 + jl;
  const float biasr = b_ih[j] + b_hh[j];
  const float biasz = b_ih[H_ + j] + b_hh[H_ + j];
  const float bihn = b_ih[2 * H_ + j];
  const float bhhn = b_hh[2 * H_ + j];

  // preload w_hh fragments (3 gates x 4 ktiles x 16B = 48 VGPRs)
  half8 wf[3][4];
#pragma unroll
  for (int g = 0; g < 3; ++g) {
    int jt = g * 64 + b;
#pragma unroll
    for (int k = 0; k < 4; ++k)
      wf[g][k] = *(const half8*)(whh + (((int64_t)jt * 32 + (w * 4 + k)) * 64 + lane) * 8);
  }

  for (int t = 0; t < TS; ++t) {
    const f16* xh_rd = xh + (t & 1) * (N_ * H_);
    f16* xh_wr = xh + ((t + 1) & 1) * (N_ * H_);

    // early independent loads (Gi; cached - only written before phaseB)
    const f16* gbase = gi2 + (int64_t)t * 3072 * 32 + n_g;
    float gvr = (float)gbase[(int64_t)j * 32];
    float gvz = (float)gbase[(int64_t)(H_ + j) * 32];
    float gvn = (float)gbase[(int64_t)(2 * H_ + j) * 32];
    // h_old: cross-wg data -> coherent (sc1) load
    unsigned hraw = aload32(xh_rd + n_g * H_ + (j & ~1));
    unsigned short hbits = (jl & 1) ? (unsigned short)(hraw >> 16) : (unsigned short)(hraw & 0xffffu);
    float hold = (float)__builtin_bit_cast(f16, hbits);

    floatx4 acc[3][2];
#pragma unroll
    for (int g = 0; g < 3; ++g)
#pragma unroll
      for (int m = 0; m < 2; ++m) { acc[g][m][0] = 0.f; acc[g][m][1] = 0.f; acc[g][m][2] = 0.f; acc[g][m][3] = 0.f; }

    // A fragments: cross-wg data -> coherent (sc1) 8B atomic loads
    half8 a0[4], a1[4];
#pragma unroll
    for (int k = 0; k < 4; ++k) {
      const f16* base = xh_rd + (w * 4 + k) * 32 + l4 * 8;
      union { half8 h; u64 u[2]; } x0, x1;
      const u64* p0 = (const u64*)(base + (int64_t)l15 * H_);
      const u64* p1 = (const u64*)(base + (int64_t)(l15 + 16) * H_);
      x0.u[0] = aload64(p0); x0.u[1] = aload64(p0 + 1);
      x1.u[0] = aload64(p1); x1.u[1] = aload64(p1 + 1);
      a0[k] = x0.h; a1[k] = x1.h;
    }
#pragma unroll
    for (int k = 0; k < 4; ++k) {
#pragma unroll
      for (int g = 0; g < 3; ++g) {
        acc[g][0] = __builtin_amdgcn_mfma_f32_16x16x32_f16(a0[k], wf[g][k], acc[g][0], 0, 0, 0);
        acc[g][1] = __builtin_amdgcn_mfma_f32_16x16x32_f16(a1[k], wf[g][k], acc[g][1], 0, 0, 0);
      }
    }

    // C/D layout: col = lane&15, row = (lane>>4)*4 + reg
#pragma unroll
    for (int g = 0; g < 3; ++g)
#pragma unroll
      for (int m = 0; m < 2; ++m)
#pragma unroll
        for (int r = 0; r < 4; ++r)
          part[w][m * 16 + l4 * 4 + r][g * 16 + l15] = acc[g][m][r];
    __syncthreads();

    float gr = biasr + gvr, gz = biasz + gvz, gin = bihn + gvn, ghn = bhhn;
#pragma unroll
    for (int ww = 0; ww < 8; ++ww) {
      gr += part[ww][n_g][jl];
      gz += part[ww][n_g][16 + jl];
      ghn += part[ww][n_g][32 + jl];
    }
    float rg = 1.f / (1.f + __expf(-gr));
    float zg = 1.f / (1.f + __expf(-gz));
    float nn = tanhf(gin + rg * ghn);
    float hnew = (1.f - zg) * nn + zg * hold;

    // pack (jl, jl^1) pair via cross-lane shuffle (partner tid = tid^32, same wave)
    unsigned short hb = __builtin_bit_cast(unsigned short, (f16)hnew);
    unsigned other = (unsigned)__shfl_xor((int)(unsigned)hb, 32, 64);
    if (!(jl & 1)) {
      unsigned packed = (unsigned)hb | (other << 16);
      __hip_atomic_store((unsigned*)(xh_wr + n_g * H_ + j), packed,
                         __ATOMIC_RELAXED, __HIP_MEMORY_SCOPE_AGENT);
      *(unsigned*)(hall + ((int64_t)t * N_ + n_g) * H_ + j) = packed;  // intra-phase only
    }
    if (t == TS - 1) out[32 + n_g * H_ + j] = hnew;

    if (t < TS - 1) gbar3(slots, (unsigned)(t + 1), b);
  }
}

// ---------------- phase C: logits GEMM + per-row sum(exp) partials ----------------

__launch_bounds__(256, 2)
__global__ void phaseC(const f16* __restrict__ hall, const f16* __restrict__ emit16,
                       const float* __restrict__ emit_b, float* __restrict__ spart) {
  const int cb = blockIdx.x % CB_;
  const int rb = blockIdx.x / CB_;
  const int tid = threadIdx.x;
  const int w = tid >> 6, lane = tid & 63;
  const int wm = w & 1, wn = w >> 1;
  const int l15 = lane & 15, l4 = lane >> 4;

  __shared__ f16 lA[128 * LDK];
  __shared__ f16 lB[128 * LDK];
  __shared__ float rs[2][128];

  floatx4 acc[4][4];
#pragma unroll
  for (int mt = 0; mt < 4; ++mt)
#pragma unroll
    for (int nt = 0; nt < 4; ++nt) { acc[mt][nt][0] = 0.f; acc[mt][nt][1] = 0.f; acc[mt][nt][2] = 0.f; acc[mt][nt][3] = 0.f; }

  const f16* gA = hall + (int64_t)rb * 128 * H_;
  const f16* gB = emit16 + (int64_t)cb * 128 * H_;

  for (int kb = 0; kb < 16; ++kb) {
    __syncthreads();
#pragma unroll
    for (int i = 0; i < 4; ++i) {
      int idx = i * 256 + tid;
      int row = idx >> 3, u = idx & 7;
      int64_t goff = (int64_t)row * H_ + kb * 64 + u * 8;
      *(half8*)(lA + row * LDK + u * 8) = *(const half8*)(gA + goff);
      *(half8*)(lB + row * LDK + u * 8) = *(const half8*)(gB + goff);
    }
    __syncthreads();
#pragma unroll
    for (int ks = 0; ks < 2; ++ks) {
      half8 af[4], bf[4];
#pragma unroll
      for (int mt = 0; mt < 4; ++mt)
        af[mt] = *(const half8*)(lA + (wm * 64 + mt * 16 + l15) * LDK + ks * 32 + l4 * 8);
#pragma unroll
      for (int nt = 0; nt < 4; ++nt)
        bf[nt] = *(const half8*)(lB + (wn * 64 + nt * 16 + l15) * LDK + ks * 32 + l4 * 8);
#pragma unroll
      for (int mt = 0; mt < 4; ++mt)
#pragma unroll
        for (int nt = 0; nt < 4; ++nt)
          acc[mt][nt] = __builtin_amdgcn_mfma_f32_16x16x32_f16(af[mt], bf[nt], acc[mt][nt], 0, 0, 0);
    }
  }

  // |logits| bounded (|h|<1, |emit_w|<~0.032) -> no max-subtraction needed
  float eb[4];
#pragma unroll
  for (int nt = 0; nt < 4; ++nt) eb[nt] = emit_b[cb * 128 + wn * 64 + nt * 16 + l15];

#pragma unroll
  for (int mt = 0; mt < 4; ++mt) {
#pragma unroll
    for (int r = 0; r < 4; ++r) {
      float s = 0.f;
#pragma unroll
      for (int nt = 0; nt < 4; ++nt) s += __expf(acc[mt][nt][r] + eb[nt]);
#pragma unroll
      for (int off = 1; off < 16; off <<= 1) s += __shfl_xor(s, off, 64);
      if (l15 == 0) rs[wn][wm * 64 + mt * 16 + l4 * 4 + r] = s;
    }
  }
  __syncthreads();
  if (tid < 128)
    spart[(int64_t)cb * MROW + rb * 128 + tid] = rs[0][tid] + rs[1][tid];
}

// ---------------- target logits + final reductions ----------------

__global__ void target_dots(const f16* __restrict__ hall, const f16* __restrict__ emit16,
                            const int* __restrict__ words, const float* __restrict__ emit_b,
                            float* __restrict__ tlog) {
  int r = blockIdx.x * 4 + (threadIdx.x >> 6);
  if (r >= TS * N_) return;
  int lane = threadIdx.x & 63;
  int t = r >> 5, n = r & 31;
  int tgt = words[n * T_ + t + 1];
  const f16* ha = hall + (int64_t)r * H_;
  const f16* ebp = emit16 + (int64_t)tgt * H_;
  float s = 0.f;
#pragma unroll
  for (int c = 0; c < 2; ++c) {
    int k = c * 512 + lane * 8;
    half8 a = *(const half8*)(ha + k);
    half8 b = *(const half8*)(ebp + k);
#pragma unroll
    for (int i = 0; i < 8; ++i) s += (float)a[i] * (float)b[i];
  }
#pragma unroll
  for (int off = 1; off < 64; off <<= 1) s += __shfl_xor(s, off, 64);
  if (lane == 0) tlog[r] = s + emit_b[tgt];
}

__global__ void reduce_lse(const float* __restrict__ spart, const float* __restrict__ tlog,
                           float* __restrict__ lval) {
  int r = blockIdx.x * blockDim.x + threadIdx.x;
  if (r >= TS * N_) return;
  float s = 0.f;
  for (int cb = 0; cb < CB_; ++cb) s += spart[(int64_t)cb * MROW + r];
  lval[r] = tlog[r] - logf(s);
}

__global__ void finalize(const float* __restrict__ lval, float* __restrict__ out) {
  __shared__ float ps[8][32];
  int n = threadIdx.x & 31, sl = threadIdx.x >> 5;
  float s = 0.f;
  for (int i = 0; i < 32; ++i) {
    int t = sl * 32 + i;
    if (t < TS) s += lval[t * N_ + n];
  }
  ps[sl][n] = s;
  __syncthreads();
  if (threadIdx.x < 32) {
    float tot = 0.f;
#pragma unroll
    for (int k = 0; k < 8; ++k) tot += ps[k][threadIdx.x];
    out[threadIdx.x] = tot;
  }
}

// ---------------- launch ----------------

extern "C" void kernel_launch(void* const* d_in, const int* in_sizes, int n_in,
                              void* d_out, int out_size, void* d_ws, size_t ws_size,
                              hipStream_t stream) {
  (void)in_sizes; (void)n_in; (void)out_size; (void)ws_size;
  const int*   words   = (const int*)d_in[0];
  const float* h0      = (const float*)d_in[1];
  const float* embed_w = (const float*)d_in[2];
  const float* w_ih    = (const float*)d_in[3];
  const float* w_hh    = (const float*)d_in[4];
  const float* b_ih    = (const float*)d_in[5];
  const float* b_hh    = (const float*)d_in[6];
  const float* emit_w  = (const float*)d_in[7];
  const float* emit_b  = (const float*)d_in[8];
  float* out = (float*)d_out;

  char* ws = (char*)d_ws;
  // ws layout (bytes), total ~100.3 MB. Aliases:
  //  - big region: Gi2 (f16, 50.1 MB, dead after phaseB) then emit16 (65.5 MB, built after phaseB)
  //  - spart (8.19 MB, phaseC) aliases wih16 (dead after gi_gemm)
  f16*      big    = (f16*)(ws + 0);                // 65,536,000
  f16*      gi2    = big;
  f16*      emit16 = big;
  f16*      whh    = (f16*)(ws + 65536000);         //  6,291,456
  f16*      wih16  = (f16*)(ws + 71827456);         //  3,145,728
  float*    spart  = (float*)(ws + 71827456);       //  8,192,000 (alias)
  f16*      xemb   = (f16*)(ws + 74973184);         //  8,388,608 (8192 rows x 512)
  f16*      xh     = (f16*)(ws + 83361792);         //    131,072
  f16*      hall   = (f16*)(ws + 83492864);         // 16,777,216
  float*    tlog   = (float*)(ws + 100270080);      //     32,640
  float*    lval   = (float*)(ws + 100302720);      //     32,640
  unsigned* slots  = (unsigned*)(ws + 100335360);   //      4,096

  hipLaunchKernelGGL(prep_whh, dim3(1536), dim3(256), 0, stream, w_hh, whh);
  hipLaunchKernelGGL(prep_wih16, dim3(768), dim3(256), 0, stream, w_ih, wih16);
  hipLaunchKernelGGL(prep_xemb, dim3(2040), dim3(256), 0, stream, words, embed_w, xemb);
  hipLaunchKernelGGL(prep_init, dim3(128), dim3(256), 0, stream, h0, xh, slots);
  hipLaunchKernelGGL(gi_gemm, dim3(RB_ * GI_CB), dim3(256), 0, stream, xemb, wih16, gi2);
  hipLaunchKernelGGL(phaseB, dim3(NWG_B), dim3(512), 0, stream, whh, gi2, xh, b_ih, b_hh, hall, out, slots);
  hipLaunchKernelGGL(prep_emit16, dim3(4096), dim3(256), 0, stream, emit_w, emit16);
  hipLaunchKernelGGL(phaseC, dim3(RB_ * CB_), dim3(256), 0, stream, hall, emit16, emit_b, spart);
  hipLaunchKernelGGL(target_dots, dim3((TS * N_ + 3) / 4), dim3(256), 0, stream, hall, emit16, words, emit_b, tlog);
  hipLaunchKernelGGL(reduce_lse, dim3((TS * N_ + 255) / 256), dim3(256), 0, stream, spart, tlog, lval);
  hipLaunchKernelGGL(finalize, dim3(1), dim3(256), 0, stream, lval, out);
}